// Round 6
// baseline (1005.295 us; speedup 1.0000x reference)
//
#include <hip/hip_runtime.h>
#include <hip/hip_bf16.h>
#include <cstdint>
#include <cstddef>

typedef unsigned short u16;
using short8  = __attribute__((ext_vector_type(8))) short;
using floatx4 = __attribute__((ext_vector_type(4))) float;

typedef __attribute__((address_space(1))) void gvoid;
typedef __attribute__((address_space(3))) void svoid;

__device__ __forceinline__ u16 f2bf(float f) {
  __hip_bfloat16 h = __float2bfloat16(f);
  return __builtin_bit_cast(u16, h);
}

__device__ __forceinline__ floatx4 mfma16(short8 a, short8 b, floatx4 c) {
  return __builtin_amdgcn_mfma_f32_16x16x32_bf16(a, b, c, 0, 0, 0);
}

// async 16B/lane global->LDS; lds base must be wave-uniform (lane i lands at base + i*16B)
__device__ __forceinline__ void glds16(const u16* g, u16* l) {
  __builtin_amdgcn_global_load_lds((gvoid*)g, (svoid*)l, 16, 0, 0);
}

// ---------------------------------------------------------------------------
// pe table: per (l, j) cos/sin.  j<16: x=l%32 rotations; j>=16: y=l/32.
__global__ void pe_kernel(float* __restrict__ pet) {
  int t = blockIdx.x * 256 + threadIdx.x;   // 1024*32
  if (t >= 32768) return;
  int l = t >> 5, j = t & 31;
  float pos   = (j < 16) ? (float)(l & 31) : (float)(l >> 5);
  float omega = powf(10000.f, -(float)(j & 15) / 16.f);
  float a = pos * omega;
  pet[2 * t]     = cosf(a);
  pet[2 * t + 1] = sinf(a);
}

// ---------------------------------------------------------------------------
// weight transpose + bf16 cast: in fp32 (K,N) row-major -> out bf16 (N,K)
// vectorized: float4 loads along N, ushort4 stores along K.  blockIdx.z = layer.
__global__ __launch_bounds__(256) void twt_kernel(const float* __restrict__ in,
                                                  u16* __restrict__ out, int K, int N) {
  size_t lofs = (size_t)blockIdx.z * K * N;
  in  += lofs;
  out += lofs;
  __shared__ float tile[32][33];
  int bx = blockIdx.x;           // over N/32
  int by = blockIdx.y;           // over K/32
  int t = threadIdx.x;
  int lk = t >> 3, ln = (t & 7) * 4;          // load: k row, 4 n cols
  float4 v = *(const float4*)(in + (size_t)(by * 32 + lk) * N + bx * 32 + ln);
  tile[lk][ln + 0] = v.x; tile[lk][ln + 1] = v.y;
  tile[lk][ln + 2] = v.z; tile[lk][ln + 3] = v.w;
  __syncthreads();
  int n = t >> 3, k0 = (t & 7) * 4;           // store: n row, 4 k cols
  ushort4 o;
  o.x = f2bf(tile[k0 + 0][n]); o.y = f2bf(tile[k0 + 1][n]);
  o.z = f2bf(tile[k0 + 2][n]); o.w = f2bf(tile[k0 + 3][n]);
  *(ushort4*)(out + (size_t)(bx * 32 + n) * K + by * 32 + k0) = o;
}

// fp32 -> bf16 elementwise
__global__ void cvt_kernel(const float* __restrict__ in, u16* __restrict__ out, int n) {
  int i = blockIdx.x * 256 + threadIdx.x;
  if (i < n) out[i] = f2bf(in[i]);
}

// cond projection, stage 1: partial[chunk][b][d] over 96-k chunks
__global__ __launch_bounds__(256) void condp_kernel(const float* __restrict__ ce,
                                                    const float* __restrict__ w,
                                                    float* __restrict__ partial) {
  int d = blockIdx.x * 256 + threadIdx.x;  // 768
  int c = blockIdx.y;                      // 16
  #pragma unroll
  for (int b = 0; b < 2; b++) {
    float acc = 0.f;
    #pragma unroll 4
    for (int k = c * 96; k < c * 96 + 96; k++) acc += ce[b * 1536 + k] * w[(size_t)k * 768 + d];
    partial[(size_t)(c * 2 + b) * 768 + d] = acc;
  }
}

// cond projection, stage 2: reduce 16 partials + bias
__global__ __launch_bounds__(256) void condr_kernel(const float* __restrict__ partial,
                                                    const float* __restrict__ bias,
                                                    float* __restrict__ out) {
  int t = blockIdx.x * 256 + threadIdx.x;  // 1536
  int b = t / 768, d = t % 768;
  float acc = bias[d];
  #pragma unroll
  for (int c = 0; c < 16; c++) acc += partial[(size_t)(c * 2 + b) * 768 + d];
  out[b * 768 + d] = acc;
}

// ---------------------------------------------------------------------------
// layernorm: x fp32 (rows,768) -> out bf16
__global__ __launch_bounds__(256) void ln_kernel(const float* __restrict__ x,
                                                 const float* __restrict__ g,
                                                 const float* __restrict__ b,
                                                 u16* __restrict__ out) {
  int row = blockIdx.x;
  const float* xr = x + (size_t)row * 768;
  int t = threadIdx.x;
  float v0 = xr[t], v1 = xr[t + 256], v2 = xr[t + 512];
  float s = v0 + v1 + v2, s2 = v0 * v0 + v1 * v1 + v2 * v2;
  #pragma unroll
  for (int o = 32; o >= 1; o >>= 1) { s += __shfl_xor(s, o); s2 += __shfl_xor(s2, o); }
  __shared__ float red[8];
  int w = t >> 6, lane = t & 63;
  if (lane == 0) { red[w] = s; red[4 + w] = s2; }
  __syncthreads();
  s  = red[0] + red[1] + red[2] + red[3];
  s2 = red[4] + red[5] + red[6] + red[7];
  float mean = s * (1.f / 768.f);
  float var  = s2 * (1.f / 768.f) - mean * mean;
  float rstd = rsqrtf(var + 1e-5f);
  u16* orow = out + (size_t)row * 768;
  orow[t]       = f2bf((v0 - mean) * rstd * g[t] + b[t]);
  orow[t + 256] = f2bf((v1 - mean) * rstd * g[t + 256] + b[t + 256]);
  orow[t + 512] = f2bf((v2 - mean) * rstd * g[t + 512] + b[t + 512]);
}

// ---------------------------------------------------------------------------
// flash attention, split-KV, fixed-shift softmax (scores in [-8,8] after rmsnorm),
// block-shared LDS staging of K/V via global_load_lds with XOR chunk swizzle.
// grid (qt, bh, split=2); block: 64 q rows x 512 kv (4 tiles of 128).
// 4 waves, wave owns 16 q rows.  Writes unnormalized partial O + row sums.
__global__ __launch_bounds__(256) void attn_split(const u16* __restrict__ qb,
                                                  const u16* __restrict__ kbuf,
                                                  const u16* __restrict__ vt,
                                                  float* __restrict__ po,
                                                  float* __restrict__ pl) {
  const int qt = blockIdx.x, bh = blockIdx.y, sp = blockIdx.z;
  const int lane = threadIdx.x & 63, w = threadIdx.x >> 6;
  const int quad = lane >> 4, l16 = lane & 15;
  __shared__ __align__(16) u16 Ks[128 * 64];
  __shared__ __align__(16) u16 Vs[64 * 128];
  __shared__ __align__(16) u16 Ps[4][16 * 136];
  const u16* Q  = qb   + (size_t)bh * 1024 * 64;
  const u16* Kp = kbuf + (size_t)bh * 1024 * 64;
  const u16* Vp = vt   + (size_t)bh * 64 * 1024;
  const int qrow0 = qt * 64 + w * 16;
  short8 aq0, aq1;
  {
    const u16* qp = Q + (size_t)(qrow0 + l16) * 64 + quad * 8;
    aq0 = *(const short8*)qp;
    aq1 = *(const short8*)(qp + 32);
  }
  floatx4 accO[4];
  #pragma unroll
  for (int i = 0; i < 4; i++) accO[i] = (floatx4){0.f, 0.f, 0.f, 0.f};
  float lsum[4] = {0.f, 0.f, 0.f, 0.f};

  const int krow_in = (lane >> 3);
  const int kchunk  = lane & 7;
  const int vrow_in = (lane >> 4);
  const int vchunk  = lane & 15;

  for (int nt = 0; nt < 4; ++nt) {
    const int kb0 = sp * 512 + nt * 128;
    __syncthreads();
    #pragma unroll
    for (int j = 0; j < 4; j++) {
      int r = w * 32 + j * 8 + krow_in;
      int g = kchunk ^ (r & 7);
      glds16(Kp + (size_t)(kb0 + r) * 64 + g * 8, Ks + (w * 32 + j * 8) * 64);
    }
    #pragma unroll
    for (int j = 0; j < 4; j++) {
      int r = w * 16 + j * 4 + vrow_in;
      int g = vchunk ^ (r & 15);
      glds16(Vp + (size_t)r * 1024 + kb0 + g * 8, Vs + (w * 16 + j * 4) * 128);
    }
    __syncthreads();

    floatx4 s[8];
    #pragma unroll
    for (int n = 0; n < 8; n++) {
      int row = n * 16 + l16;
      int c0 = quad ^ (l16 & 7);
      short8 b0 = *(const short8*)&Ks[row * 64 + c0 * 8];
      short8 b1 = *(const short8*)&Ks[row * 64 + (c0 ^ 4) * 8];
      floatx4 z = (floatx4){0.f, 0.f, 0.f, 0.f};
      z = mfma16(aq0, b0, z);
      s[n] = mfma16(aq1, b1, z);
    }
    #pragma unroll
    for (int n = 0; n < 8; n++) {
      #pragma unroll
      for (int r = 0; r < 4; r++) {
        float pv = __expf(s[n][r] - 8.f);
        lsum[r] += pv;
        Ps[w][(quad * 4 + r) * 136 + n * 16 + l16] = f2bf(pv);
      }
    }
    #pragma unroll
    for (int kt = 0; kt < 4; kt++) {
      short8 ap = *(const short8*)&Ps[w][l16 * 136 + kt * 32 + quad * 8];
      #pragma unroll
      for (int dt = 0; dt < 4; dt++) {
        int vrow = dt * 16 + l16;
        int c = (kt * 4 + quad) ^ l16;
        short8 bv = *(const short8*)&Vs[vrow * 128 + c * 8];
        accO[dt] = mfma16(ap, bv, accO[dt]);
      }
    }
  }
  #pragma unroll
  for (int r = 0; r < 4; r++) {
    #pragma unroll
    for (int o = 1; o < 16; o <<= 1) lsum[r] += __shfl_xor(lsum[r], o);
  }
  const size_t sb = (size_t)(sp * 24 + bh) * 1024;
  #pragma unroll
  for (int r = 0; r < 4; r++) {
    int lr = qrow0 + quad * 4 + r;
    if (l16 == 0) pl[sb + lr] = lsum[r];
    #pragma unroll
    for (int dt = 0; dt < 4; dt++)
      po[(sb + lr) * 64 + dt * 16 + l16] = accO[dt][r];
  }
}

// ---------------------------------------------------------------------------
// GEMM: C(M,N) = A(M,K) @ Bt(N,K)^T, bf16 in, fp32 acc.
// Async-DMA staged (global_load_lds width 16, XOR chunk swizzle, linear LDS).
// Non-AFUSE: DEPTH-2 pipeline, triple-buffered LDS, counted vmcnt(NG)+s_barrier.
// AFUSE (proj): A rows = normalized attention output computed on the fly from
//   po/pl (split-KV partials); K-step it == head it.  A staged via regs
//   (issue-early/write-late), B via glds16; 2-buffer drain-0 loop.
// Tile BM x BN, 4 waves in 2x2; each wave (BM/2)x(BN/2).
// EPI 0: +bias -> Cf (or Cb).  1: +bias +cond[row>>10] -> Cf.
// EPI 2: +bias +extra[row,col] -> Cf and Cb.  3: gelu(+bias) -> Cb.
// EPI 4 (qkv): q/k blocks: fused rmsnorm+rope -> qb/kb.  v blocks: LDS-bounce
//   transpose -> vt (bh,d,l) directly.  Region is block-uniform (768%128 via
//   col-block 128: n0/768).
template <int EPI, int BM, int BN, bool AFUSE>
__global__ __launch_bounds__(256) void gemm_bt(const u16* __restrict__ A,
                                               const u16* __restrict__ Bt,
                                               const float* __restrict__ bias,
                                               const float* extra,
                                               float* Cf, u16* Cb, int M, int N, int K,
                                               const float* qsc, const float* ksc,
                                               const float* petp,
                                               u16* qb, u16* kb, u16* vt,
                                               const float* po, const float* pl) {
  constexpr int ROWS = BM + BN;          // A rows then B rows
  constexpr int RPW  = ROWS / 4;         // rows staged per wave per K-step
  constexpr int NG   = RPW / 8;          // glds16 per wave per K-step (each does 8 rows)
  constexpr int MT   = BM / 32;          // m-frags per wave
  constexpr int NTW  = BN / 32;          // n-frags per wave
  constexpr int NBUF = AFUSE ? 2 : 3;
  __shared__ __align__(16) u16 S[NBUF][ROWS * 64];
  const int t = threadIdx.x;
  const int lane = t & 63, w = t >> 6;
  const int quad = lane >> 4, l16 = lane & 15;
  const int m0 = blockIdx.y * BM, n0 = blockIdx.x * BN;
  const int wm = (w >> 1) * (BM / 2), wn = (w & 1) * (BN / 2);

  floatx4 acc[MT][NTW];
  #pragma unroll
  for (int i = 0; i < MT; i++)
    #pragma unroll
    for (int j = 0; j < NTW; j++) acc[i][j] = (floatx4){0.f, 0.f, 0.f, 0.f};

  // staging descriptors: glds j covers rows [w*RPW + j*8, +8); lane -> (row, chunk).
  // source chunk g = c ^ (row&7): inverse-swizzled source, linear LDS dest, so the
  // swizzled ds_read below sees conflict-free banks (rule #21: both sides or neither).
  const u16* gsrc[NG];
  int loff[NG];
  #pragma unroll
  for (int j = 0; j < NG; j++) {
    int r = w * RPW + j * 8 + (lane >> 3);
    int c = lane & 7;
    int g = c ^ (r & 7);
    const u16* base = (r < BM) ? (A + (size_t)(m0 + r) * K)
                               : (Bt + (size_t)(n0 + r - BM) * K);
    gsrc[j] = base + g * 8;
    loff[j] = (w * RPW + j * 8) * 64;    // wave-uniform LDS base (u16 units)
  }

  const int NIT = K >> 6;

  auto compute = [&](int buf) {
    const u16* Sb = &S[buf][0];
    #pragma unroll
    for (int kk = 0; kk < 2; kk++) {
      short8 af[MT], bfr[NTW];
      #pragma unroll
      for (int mt = 0; mt < MT; mt++) {
        int ra = wm + mt * 16 + l16;
        af[mt] = *(const short8*)&Sb[ra * 64 + ((((kk << 2) | quad)) ^ (ra & 7)) * 8];
      }
      #pragma unroll
      for (int nt = 0; nt < NTW; nt++) {
        int rb = BM + wn + nt * 16 + l16;
        bfr[nt] = *(const short8*)&Sb[rb * 64 + ((((kk << 2) | quad)) ^ (rb & 7)) * 8];
      }
      #pragma unroll
      for (int mt = 0; mt < MT; mt++)
        #pragma unroll
        for (int nt = 0; nt < NTW; nt++)
          acc[mt][nt] = mfma16(af[mt], bfr[nt], acc[mt][nt]);
    }
  };

  if constexpr (AFUSE) {
    // ---- fused attn-combine A-staging (BM=BN=64, K=768, NIT=12) ----
    __shared__ float den[768];           // 1/(pl0+pl1) per (head, local row)
    const int blk = m0 >> 10, l0 = m0 & 1023;
    for (int q = t; q < 768; q += 256) {
      int hh = q >> 6, r = q & 63;
      float d0 = pl[((size_t)(blk * 12 + hh)) * 1024 + l0 + r];
      float d1 = pl[((size_t)(24 + blk * 12 + hh)) * 1024 + l0 + r];
      den[q] = 1.f / (d0 + d1);
    }
    __syncthreads();

    const int ar = w * 32 + (lane >> 3);  // A row base (w<2), + j*8
    const int ac = lane & 7;              // 8-d chunk
    float4 regs[16];

    auto stageA = [&](int it) {
      #pragma unroll
      for (int j = 0; j < 4; j++) {
        int r = ar + j * 8;
        size_t base = ((size_t)(blk * 12 + it) * 1024 + l0 + r) * 64 + ac * 8;
        regs[j * 4 + 0] = *(const float4*)(po + base);
        regs[j * 4 + 1] = *(const float4*)(po + base + 4);
        regs[j * 4 + 2] = *(const float4*)(po + base + (size_t)24 * 65536);
        regs[j * 4 + 3] = *(const float4*)(po + base + 4 + (size_t)24 * 65536);
      }
    };
    auto writeA = [&](int it, int buf) {
      #pragma unroll
      for (int j = 0; j < 4; j++) {
        int r = ar + j * 8;
        float dv = den[it * 64 + r];
        u16 o[8];
        float4 a0 = regs[j * 4 + 0], a1 = regs[j * 4 + 1];
        float4 b0 = regs[j * 4 + 2], b1 = regs[j * 4 + 3];
        o[0] = f2bf((a0.x + b0.x) * dv); o[1] = f2bf((a0.y + b0.y) * dv);
        o[2] = f2bf((a0.z + b0.z) * dv); o[3] = f2bf((a0.w + b0.w) * dv);
        o[4] = f2bf((a1.x + b1.x) * dv); o[5] = f2bf((a1.y + b1.y) * dv);
        o[6] = f2bf((a1.z + b1.z) * dv); o[7] = f2bf((a1.w + b1.w) * dv);
        *(short8*)&S[buf][r * 64 + (ac ^ (r & 7)) * 8] = *(short8*)o;
      }
    };

    // prologue
    if (w < 2) { stageA(0); writeA(0, 0); }
    else {
      #pragma unroll
      for (int j = 0; j < NG; j++) glds16(gsrc[j], &S[0][loff[j]]);
    }
    __syncthreads();

    int cur = 0;
    for (int it = 0; it < 12; ++it) {
      if (it + 1 < 12) {
        if (w < 2) stageA(it + 1);
        else {
          #pragma unroll
          for (int j = 0; j < NG; j++) glds16(gsrc[j] + (it + 1) * 64, &S[cur ^ 1][loff[j]]);
        }
      }
      compute(cur);
      if (it + 1 < 12) {
        if (w < 2) writeA(it + 1, cur ^ 1);
        __syncthreads();
      }
      cur ^= 1;
    }
  } else {
    // ---- depth-2 counted-vmcnt pipeline ----
    #pragma unroll
    for (int j = 0; j < NG; j++) glds16(gsrc[j], &S[0][loff[j]]);
    #pragma unroll
    for (int j = 0; j < NG; j++) glds16(gsrc[j] + 64, &S[1][loff[j]]);
    asm volatile("s_waitcnt vmcnt(%0)" :: "n"(NG) : "memory");
    __builtin_amdgcn_s_barrier();
    asm volatile("" ::: "memory");

    int bufc = 0;
    for (int it = 0; it < NIT; ++it) {
      if (it + 2 < NIT) {
        int bufp = bufc + 2; if (bufp >= 3) bufp -= 3;
        #pragma unroll
        for (int j = 0; j < NG; j++) glds16(gsrc[j] + (it + 2) * 64, &S[bufp][loff[j]]);
      }
      compute(bufc);
      if (it + 1 < NIT) {
        if (it + 2 < NIT) asm volatile("s_waitcnt vmcnt(%0)" :: "n"(NG) : "memory");
        else              asm volatile("s_waitcnt vmcnt(0)" ::: "memory");
        __builtin_amdgcn_s_barrier();
        asm volatile("" ::: "memory");
      }
      bufc = (bufc + 1 == 3) ? 0 : bufc + 1;
    }
  }

  if (EPI == 4) {
    const int reg = n0 / 768;                 // 0=q, 1=k, 2=v (block-uniform)
    if (reg == 2) {
      // LDS-bounce transpose of the v quadrant -> vt (bh, d, l) directly.
      __syncthreads();                        // all waves done reading S
      u16* T = (u16*)&S[0][0];                // [64][130] padded (stride 65 dwords)
      #pragma unroll
      for (int mt = 0; mt < MT; mt++)
        #pragma unroll
        for (int nt = 0; nt < NTW; nt++)
          #pragma unroll
          for (int r = 0; r < 4; r++)
            T[(wm + mt * 16 + quad * 4 + r) * 130 + wn + nt * 16 + l16] =
                f2bf(acc[mt][nt][r]);
      __syncthreads();
      int d = t >> 1, lh = (t & 1) * 32;
      int head = ((n0 - 1536) >> 6) + (d >> 6), d63 = d & 63;
      u16 o[32];
      #pragma unroll
      for (int i2 = 0; i2 < 32; i2++) o[i2] = T[(lh + i2) * 130 + d];
      u16* dst = vt + ((size_t)((m0 >> 10) * 12 + head) * 64 + d63) * 1024
                    + (m0 & 1023) + lh;
      #pragma unroll
      for (int i2 = 0; i2 < 4; i2++) *(short8*)(dst + i2 * 8) = *(short8*)&o[i2 * 8];
      return;
    }
    // q/k: fused rmsnorm + rope.  wave quadrant = 32 seq rows x one 64-wide head.
    const int cb  = n0 + wn;
    const int hh  = (cb - reg * 768) >> 6;
    #pragma unroll
    for (int mt = 0; mt < MT; mt++) {
      #pragma unroll
      for (int r = 0; r < 4; r++) {
        int grow = m0 + wm + mt * 16 + quad * 4 + r;
        int bI = grow >> 10, lI = grow & 1023;
        float s2 = 0.f;
        #pragma unroll
        for (int nt = 0; nt < NTW; nt++) s2 += acc[mt][nt][r] * acc[mt][nt][r];
        #pragma unroll
        for (int o = 1; o < 16; o <<= 1) s2 += __shfl_xor(s2, o);
        float rstd = rsqrtf(s2 * (1.f / 64.f) + 1e-6f);
        const float* sc = reg ? ksc : qsc;
        u16* dst = (reg ? kb : qb) + ((size_t)(bI * 12 + hh) * 1024 + lI) * 64;
        #pragma unroll
        for (int nt = 0; nt < NTW; nt++) {
          int d = nt * 16 + l16;
          float v = acc[mt][nt][r] * rstd * sc[d];
          float cv = petp[((lI * 32) + (d >> 1)) * 2];
          float sv = petp[((lI * 32) + (d >> 1)) * 2 + 1];
          float ov = __shfl_xor(v, 1);
          float rv = (d & 1) ? (sv * ov + cv * v) : (cv * v - sv * ov);
          if (reg == 0) rv *= 0.125f;
          dst[d] = f2bf(rv);
        }
      }
    }
    return;
  }

  #pragma unroll
  for (int mt = 0; mt < MT; mt++) {
    #pragma unroll
    for (int nt = 0; nt < NTW; nt++) {
      int col = n0 + wn + nt * 16 + l16;
      float bcol = bias ? bias[col] : 0.f;
      #pragma unroll
      for (int r = 0; r < 4; r++) {
        int row = m0 + wm + mt * 16 + quad * 4 + r;
        float v = acc[mt][nt][r] + bcol;
        if (EPI == 1) v += extra[(row >> 10) * N + col];
        if (EPI == 2) v += extra[(size_t)row * N + col];
        if (EPI == 3) v = 0.5f * v * (1.f + erff(v * 0.70710678118654752f));
        if (Cf) Cf[(size_t)row * N + col] = v;
        if (Cb) Cb[(size_t)row * N + col] = f2bf(v);
      }
    }
  }
}

// ---------------------------------------------------------------------------
extern "C" void kernel_launch(void* const* d_in, const int* in_sizes, int n_in,
                              void* d_out, int out_size, void* d_ws, size_t ws_size,
                              hipStream_t stream) {
  const float* sf   = (const float*)d_in[0];
  const float* ce   = (const float*)d_in[2];
  const float* sw   = (const float*)d_in[3];
  const float* sb   = (const float*)d_in[4];
  const float* cw   = (const float*)d_in[5];
  const float* cb   = (const float*)d_in[6];
  const float* ln1g = (const float*)d_in[7];
  const float* ln1b = (const float*)d_in[8];
  const float* qkvw = (const float*)d_in[9];
  const float* qsc  = (const float*)d_in[10];
  const float* ksc  = (const float*)d_in[11];
  const float* pw   = (const float*)d_in[12];
  const float* pb   = (const float*)d_in[13];
  const float* ln2g = (const float*)d_in[16];
  const float* ln2b = (const float*)d_in[17];
  const float* w1   = (const float*)d_in[18];
  const float* b1   = (const float*)d_in[19];
  const float* w2   = (const float*)d_in[20];
  const float* b2   = (const float*)d_in[21];
  const float* ow   = (const float*)d_in[22];
  const float* ob   = (const float*)d_in[23];

  char* p = (char*)d_ws;
  auto alloc = [&](size_t bytes) { char* r = p; p += (bytes + 255) & ~(size_t)255; return r; };
  float* pet  = (float*)alloc((size_t)1024 * 32 * 2 * 4);
  u16* swT    = (u16*)alloc((size_t)768 * 768 * 2);
  u16* owT    = (u16*)alloc((size_t)768 * 768 * 2);
  u16* qkvT   = (u16*)alloc((size_t)6 * 2304 * 768 * 2);
  u16* pwT    = (u16*)alloc((size_t)6 * 768 * 768 * 2);
  u16* w1T    = (u16*)alloc((size_t)6 * 3072 * 768 * 2);
  u16* w2T    = (u16*)alloc((size_t)6 * 768 * 3072 * 2);
  u16* sfb    = (u16*)alloc((size_t)2048 * 768 * 2);
  float* cpar = (float*)alloc((size_t)32 * 768 * 4);
  float* cond = (float*)alloc((size_t)2 * 768 * 4);
  float* x    = (float*)alloc((size_t)2048 * 768 * 4);
  u16* xb     = (u16*)alloc((size_t)2048 * 768 * 2);
  u16* h      = (u16*)alloc((size_t)2048 * 768 * 2);
  u16* qbuf   = (u16*)alloc((size_t)2048 * 768 * 2);
  u16* kbuf   = (u16*)alloc((size_t)2048 * 768 * 2);
  u16* vtb    = (u16*)alloc((size_t)2048 * 768 * 2);
  u16* gbuf   = (u16*)alloc((size_t)2048 * 3072 * 2);
  float* po   = (float*)alloc((size_t)2 * 24 * 1024 * 64 * 4);
  float* pl   = (float*)alloc((size_t)2 * 24 * 1024 * 4);

  pe_kernel<<<128, 256, 0, stream>>>(pet);
  twt_kernel<<<dim3(24, 24, 1), 256, 0, stream>>>(sw, swT, 768, 768);
  twt_kernel<<<dim3(24, 24, 1), 256, 0, stream>>>(ow, owT, 768, 768);
  twt_kernel<<<dim3(72, 24, 6), 256, 0, stream>>>(qkvw, qkvT, 768, 2304);
  twt_kernel<<<dim3(24, 24, 6), 256, 0, stream>>>(pw, pwT, 768, 768);
  twt_kernel<<<dim3(96, 24, 6), 256, 0, stream>>>(w1, w1T, 768, 3072);
  twt_kernel<<<dim3(24, 96, 6), 256, 0, stream>>>(w2, w2T, 3072, 768);
  cvt_kernel<<<(2048 * 768) / 256, 256, 0, stream>>>(sf, sfb, 2048 * 768);
  condp_kernel<<<dim3(3, 16), 256, 0, stream>>>(ce, cw, cpar);
  condr_kernel<<<6, 256, 0, stream>>>(cpar, cb, cond);

  gemm_bt<1, 64, 64, false><<<dim3(12, 32), 256, 0, stream>>>(sfb, swT, sb, cond, x, nullptr,
      2048, 768, 768, nullptr, nullptr, nullptr, nullptr, nullptr, nullptr, nullptr, nullptr);

  for (int i = 0; i < 6; i++) {
    ln_kernel<<<2048, 256, 0, stream>>>(x, ln1g + i * 768, ln1b + i * 768, h);
    gemm_bt<4, 64, 128, false><<<dim3(18, 32), 256, 0, stream>>>(h, qkvT + (size_t)i * 2304 * 768,
        nullptr, nullptr, nullptr, nullptr, 2048, 2304, 768,
        qsc + i * 64, ksc + i * 64, pet, qbuf, kbuf, vtb, nullptr, nullptr);
    attn_split<<<dim3(16, 24, 2), 256, 0, stream>>>(qbuf, kbuf, vtb, po, pl);
    gemm_bt<2, 64, 64, true><<<dim3(12, 32), 256, 0, stream>>>(h, pwT + (size_t)i * 768 * 768,
        pb + i * 768, x, x, nullptr, 2048, 768, 768,
        nullptr, nullptr, nullptr, nullptr, nullptr, nullptr, po, pl);
    ln_kernel<<<2048, 256, 0, stream>>>(x, ln2g + i * 768, ln2b + i * 768, h);
    gemm_bt<3, 64, 128, false><<<dim3(24, 32), 256, 0, stream>>>(h, w1T + (size_t)i * 3072 * 768,
        b1 + i * 3072, nullptr, nullptr, gbuf, 2048, 3072, 768,
        nullptr, nullptr, nullptr, nullptr, nullptr, nullptr, nullptr, nullptr);
    gemm_bt<2, 64, 64, false><<<dim3(12, 32), 256, 0, stream>>>(gbuf, w2T + (size_t)i * 768 * 3072,
        b2 + i * 768, x, x, (i == 5) ? xb : nullptr, 2048, 768, 3072,
        nullptr, nullptr, nullptr, nullptr, nullptr, nullptr, nullptr, nullptr);
  }
  gemm_bt<0, 64, 64, false><<<dim3(12, 32), 256, 0, stream>>>(xb, owT, ob, nullptr, (float*)d_out, nullptr,
      2048, 768, 768, nullptr, nullptr, nullptr, nullptr, nullptr, nullptr, nullptr, nullptr);
}

// Round 7
// 967.253 us; speedup vs baseline: 1.0393x; 1.0393x over previous
//
#include <hip/hip_runtime.h>
#include <hip/hip_bf16.h>
#include <cstdint>
#include <cstddef>

typedef unsigned short u16;
using short8  = __attribute__((ext_vector_type(8))) short;
using floatx4 = __attribute__((ext_vector_type(4))) float;

typedef __attribute__((address_space(1))) void gvoid;
typedef __attribute__((address_space(3))) void svoid;

__device__ __forceinline__ u16 f2bf(float f) {
  __hip_bfloat16 h = __float2bfloat16(f);
  return __builtin_bit_cast(u16, h);
}

__device__ __forceinline__ floatx4 mfma16(short8 a, short8 b, floatx4 c) {
  return __builtin_amdgcn_mfma_f32_16x16x32_bf16(a, b, c, 0, 0, 0);
}

// async 16B/lane global->LDS; lds base must be wave-uniform (lane i lands at base + i*16B)
__device__ __forceinline__ void glds16(const u16* g, u16* l) {
  __builtin_amdgcn_global_load_lds((gvoid*)g, (svoid*)l, 16, 0, 0);
}

// ---------------------------------------------------------------------------
// pe table: per (l, j) cos/sin.  j<16: x=l%32 rotations; j>=16: y=l/32.
__global__ void pe_kernel(float* __restrict__ pet) {
  int t = blockIdx.x * 256 + threadIdx.x;   // 1024*32
  if (t >= 32768) return;
  int l = t >> 5, j = t & 31;
  float pos   = (j < 16) ? (float)(l & 31) : (float)(l >> 5);
  float omega = powf(10000.f, -(float)(j & 15) / 16.f);
  float a = pos * omega;
  pet[2 * t]     = cosf(a);
  pet[2 * t + 1] = sinf(a);
}

// ---------------------------------------------------------------------------
// weight transpose + bf16 cast: in fp32 (K,N) row-major -> out bf16 (N,K)
// vectorized: float4 loads along N, ushort4 stores along K.  blockIdx.z = layer.
__global__ __launch_bounds__(256) void twt_kernel(const float* __restrict__ in,
                                                  u16* __restrict__ out, int K, int N) {
  size_t lofs = (size_t)blockIdx.z * K * N;
  in  += lofs;
  out += lofs;
  __shared__ float tile[32][33];
  int bx = blockIdx.x;           // over N/32
  int by = blockIdx.y;           // over K/32
  int t = threadIdx.x;
  int lk = t >> 3, ln = (t & 7) * 4;          // load: k row, 4 n cols
  float4 v = *(const float4*)(in + (size_t)(by * 32 + lk) * N + bx * 32 + ln);
  tile[lk][ln + 0] = v.x; tile[lk][ln + 1] = v.y;
  tile[lk][ln + 2] = v.z; tile[lk][ln + 3] = v.w;
  __syncthreads();
  int n = t >> 3, k0 = (t & 7) * 4;           // store: n row, 4 k cols
  ushort4 o;
  o.x = f2bf(tile[k0 + 0][n]); o.y = f2bf(tile[k0 + 1][n]);
  o.z = f2bf(tile[k0 + 2][n]); o.w = f2bf(tile[k0 + 3][n]);
  *(ushort4*)(out + (size_t)(bx * 32 + n) * K + by * 32 + k0) = o;
}

// fp32 -> bf16 elementwise
__global__ void cvt_kernel(const float* __restrict__ in, u16* __restrict__ out, int n) {
  int i = blockIdx.x * 256 + threadIdx.x;
  if (i < n) out[i] = f2bf(in[i]);
}

// cond projection, stage 1: partial[chunk][b][d] over 96-k chunks
__global__ __launch_bounds__(256) void condp_kernel(const float* __restrict__ ce,
                                                    const float* __restrict__ w,
                                                    float* __restrict__ partial) {
  int d = blockIdx.x * 256 + threadIdx.x;  // 768
  int c = blockIdx.y;                      // 16
  #pragma unroll
  for (int b = 0; b < 2; b++) {
    float acc = 0.f;
    #pragma unroll 4
    for (int k = c * 96; k < c * 96 + 96; k++) acc += ce[b * 1536 + k] * w[(size_t)k * 768 + d];
    partial[(size_t)(c * 2 + b) * 768 + d] = acc;
  }
}

// cond projection, stage 2: reduce 16 partials + bias
__global__ __launch_bounds__(256) void condr_kernel(const float* __restrict__ partial,
                                                    const float* __restrict__ bias,
                                                    float* __restrict__ out) {
  int t = blockIdx.x * 256 + threadIdx.x;  // 1536
  int b = t / 768, d = t % 768;
  float acc = bias[d];
  #pragma unroll
  for (int c = 0; c < 16; c++) acc += partial[(size_t)(c * 2 + b) * 768 + d];
  out[b * 768 + d] = acc;
}

// ---------------------------------------------------------------------------
// layernorm: x fp32 (rows,768) -> out bf16
__global__ __launch_bounds__(256) void ln_kernel(const float* __restrict__ x,
                                                 const float* __restrict__ g,
                                                 const float* __restrict__ b,
                                                 u16* __restrict__ out) {
  int row = blockIdx.x;
  const float* xr = x + (size_t)row * 768;
  int t = threadIdx.x;
  float v0 = xr[t], v1 = xr[t + 256], v2 = xr[t + 512];
  float s = v0 + v1 + v2, s2 = v0 * v0 + v1 * v1 + v2 * v2;
  #pragma unroll
  for (int o = 32; o >= 1; o >>= 1) { s += __shfl_xor(s, o); s2 += __shfl_xor(s2, o); }
  __shared__ float red[8];
  int w = t >> 6, lane = t & 63;
  if (lane == 0) { red[w] = s; red[4 + w] = s2; }
  __syncthreads();
  s  = red[0] + red[1] + red[2] + red[3];
  s2 = red[4] + red[5] + red[6] + red[7];
  float mean = s * (1.f / 768.f);
  float var  = s2 * (1.f / 768.f) - mean * mean;
  float rstd = rsqrtf(var + 1e-5f);
  u16* orow = out + (size_t)row * 768;
  orow[t]       = f2bf((v0 - mean) * rstd * g[t] + b[t]);
  orow[t + 256] = f2bf((v1 - mean) * rstd * g[t + 256] + b[t + 256]);
  orow[t + 512] = f2bf((v2 - mean) * rstd * g[t + 512] + b[t + 512]);
}

// ---------------------------------------------------------------------------
// single-pass flash attention (no KV split), fixed-shift softmax (scores in
// [-8,8] after rmsnorm), LDS staging of K/V via global_load_lds with XOR chunk
// swizzle.  grid (qt=32, bh=24); block 128 threads = 2 waves x 16 q-rows.
// Each block sweeps all 8 KV-tiles of 128 and writes NORMALIZED bf16 obuf
// directly (exact softmax, no partial round-trip).
// LDS 41KB -> 3 blocks/CU; 768 blocks = exactly one resident round.
__global__ __launch_bounds__(128) void attn_one(const u16* __restrict__ qb,
                                                const u16* __restrict__ kbuf,
                                                const u16* __restrict__ vt,
                                                u16* __restrict__ obuf) {
  const int qt = blockIdx.x, bh = blockIdx.y;
  const int lane = threadIdx.x & 63, w = threadIdx.x >> 6;   // w in {0,1}
  const int quad = lane >> 4, l16 = lane & 15;
  __shared__ __align__(16) u16 Ks[128 * 64];
  __shared__ __align__(16) u16 Vs[64 * 128];
  __shared__ __align__(16) u16 Ps[2][16 * 136];
  const u16* Q  = qb   + (size_t)bh * 1024 * 64;
  const u16* Kp = kbuf + (size_t)bh * 1024 * 64;
  const u16* Vp = vt   + (size_t)bh * 64 * 1024;
  const int qrow0 = qt * 32 + w * 16;
  short8 aq0, aq1;
  {
    const u16* qp = Q + (size_t)(qrow0 + l16) * 64 + quad * 8;
    aq0 = *(const short8*)qp;
    aq1 = *(const short8*)(qp + 32);
  }
  floatx4 accO[4];
  #pragma unroll
  for (int i = 0; i < 4; i++) accO[i] = (floatx4){0.f, 0.f, 0.f, 0.f};
  float lsum[4] = {0.f, 0.f, 0.f, 0.f};

  const int krow_in = (lane >> 3);
  const int kchunk  = lane & 7;
  const int vrow_in = (lane >> 4);
  const int vchunk  = lane & 15;

  for (int nt = 0; nt < 8; ++nt) {
    const int kb0 = nt * 128;
    __syncthreads();
    #pragma unroll
    for (int j = 0; j < 8; j++) {        // K: 64 rows per wave
      int r = w * 64 + j * 8 + krow_in;
      int g = kchunk ^ (r & 7);
      glds16(Kp + (size_t)(kb0 + r) * 64 + g * 8, Ks + (w * 64 + j * 8) * 64);
    }
    #pragma unroll
    for (int j = 0; j < 8; j++) {        // V: 32 d-rows per wave
      int r = w * 32 + j * 4 + vrow_in;
      int g = vchunk ^ (r & 15);
      glds16(Vp + (size_t)r * 1024 + kb0 + g * 8, Vs + (w * 32 + j * 4) * 128);
    }
    __syncthreads();

    floatx4 s[8];
    #pragma unroll
    for (int n = 0; n < 8; n++) {
      int row = n * 16 + l16;
      int c0 = quad ^ (l16 & 7);
      short8 b0 = *(const short8*)&Ks[row * 64 + c0 * 8];
      short8 b1 = *(const short8*)&Ks[row * 64 + (c0 ^ 4) * 8];
      floatx4 z = (floatx4){0.f, 0.f, 0.f, 0.f};
      z = mfma16(aq0, b0, z);
      s[n] = mfma16(aq1, b1, z);
    }
    #pragma unroll
    for (int n = 0; n < 8; n++) {
      #pragma unroll
      for (int r = 0; r < 4; r++) {
        float pv = __expf(s[n][r] - 8.f);
        lsum[r] += pv;
        Ps[w][(quad * 4 + r) * 136 + n * 16 + l16] = f2bf(pv);
      }
    }
    #pragma unroll
    for (int kt = 0; kt < 4; kt++) {
      short8 ap = *(const short8*)&Ps[w][l16 * 136 + kt * 32 + quad * 8];
      #pragma unroll
      for (int dt = 0; dt < 4; dt++) {
        int vrow = dt * 16 + l16;
        int c = (kt * 4 + quad) ^ l16;
        short8 bv = *(const short8*)&Vs[vrow * 128 + c * 8];
        accO[dt] = mfma16(ap, bv, accO[dt]);
      }
    }
  }
  #pragma unroll
  for (int r = 0; r < 4; r++) {
    #pragma unroll
    for (int o = 1; o < 16; o <<= 1) lsum[r] += __shfl_xor(lsum[r], o);
  }
  const int b = bh / 12, h = bh % 12;
  #pragma unroll
  for (int r = 0; r < 4; r++) {
    int lr = qrow0 + quad * 4 + r;
    float inv = 1.f / lsum[r];
    u16* dst = obuf + ((size_t)(b * 1024 + lr)) * 768 + h * 64;
    #pragma unroll
    for (int dt = 0; dt < 4; dt++) dst[dt * 16 + l16] = f2bf(accO[dt][r] * inv);
  }
}

// ---------------------------------------------------------------------------
// GEMM: C(M,N) = A(M,K) @ Bt(N,K)^T, bf16 in, fp32 acc.
// Async-DMA staged (global_load_lds width 16, XOR chunk swizzle, linear LDS),
// DEPTH-2 pipeline: triple-buffered LDS, counted s_waitcnt vmcnt(NG) + raw
// s_barrier (tile t+2's DMA stays in flight across the barrier).
// Tile BM x BN, 4 waves in 2x2; each wave (BM/2)x(BN/2).
// EPI 0: +bias -> Cf (or Cb).  1: +bias +cond[row>>10] -> Cf.
// EPI 2: +bias +extra[row,col] -> Cf and Cb.  3: gelu(+bias) -> Cb.
// EPI 4 (qkv): q/k blocks: fused rmsnorm+rope -> qb/kb.  v blocks: LDS-bounce
//   transpose -> vt (bh,d,l) directly.  Region is block-uniform (n0/768).
template <int EPI, int BM, int BN>
__global__ __launch_bounds__(256) void gemm_bt(const u16* __restrict__ A,
                                               const u16* __restrict__ Bt,
                                               const float* __restrict__ bias,
                                               const float* extra,
                                               float* Cf, u16* Cb, int M, int N, int K,
                                               const float* qsc, const float* ksc,
                                               const float* petp,
                                               u16* qb, u16* kb, u16* vt) {
  constexpr int ROWS = BM + BN;          // A rows then B rows
  constexpr int RPW  = ROWS / 4;         // rows staged per wave per K-step
  constexpr int NG   = RPW / 8;          // glds16 per wave per K-step (each does 8 rows)
  constexpr int MT   = BM / 32;          // m-frags per wave
  constexpr int NTW  = BN / 32;          // n-frags per wave
  __shared__ __align__(16) u16 S[3][ROWS * 64];
  const int t = threadIdx.x;
  const int lane = t & 63, w = t >> 6;
  const int quad = lane >> 4, l16 = lane & 15;
  const int m0 = blockIdx.y * BM, n0 = blockIdx.x * BN;
  const int wm = (w >> 1) * (BM / 2), wn = (w & 1) * (BN / 2);

  floatx4 acc[MT][NTW];
  #pragma unroll
  for (int i = 0; i < MT; i++)
    #pragma unroll
    for (int j = 0; j < NTW; j++) acc[i][j] = (floatx4){0.f, 0.f, 0.f, 0.f};

  // staging descriptors: glds j covers rows [w*RPW + j*8, +8); lane -> (row, chunk).
  // source chunk g = c ^ (row&7): inverse-swizzled source, linear LDS dest, so the
  // swizzled ds_read below sees conflict-free banks (rule #21: both sides or neither).
  const u16* gsrc[NG];
  int loff[NG];
  #pragma unroll
  for (int j = 0; j < NG; j++) {
    int r = w * RPW + j * 8 + (lane >> 3);
    int c = lane & 7;
    int g = c ^ (r & 7);
    const u16* base = (r < BM) ? (A + (size_t)(m0 + r) * K)
                               : (Bt + (size_t)(n0 + r - BM) * K);
    gsrc[j] = base + g * 8;
    loff[j] = (w * RPW + j * 8) * 64;    // wave-uniform LDS base (u16 units)
  }

  const int NIT = K >> 6;

  auto compute = [&](int buf) {
    const u16* Sb = &S[buf][0];
    #pragma unroll
    for (int kk = 0; kk < 2; kk++) {
      short8 af[MT], bfr[NTW];
      #pragma unroll
      for (int mt = 0; mt < MT; mt++) {
        int ra = wm + mt * 16 + l16;
        af[mt] = *(const short8*)&Sb[ra * 64 + ((((kk << 2) | quad)) ^ (ra & 7)) * 8];
      }
      #pragma unroll
      for (int nt = 0; nt < NTW; nt++) {
        int rb = BM + wn + nt * 16 + l16;
        bfr[nt] = *(const short8*)&Sb[rb * 64 + ((((kk << 2) | quad)) ^ (rb & 7)) * 8];
      }
      #pragma unroll
      for (int mt = 0; mt < MT; mt++)
        #pragma unroll
        for (int nt = 0; nt < NTW; nt++)
          acc[mt][nt] = mfma16(af[mt], bfr[nt], acc[mt][nt]);
    }
  };

  // prologue: issue tiles 0 and 1, wait for tile 0 only (tile 1 stays in flight)
  #pragma unroll
  for (int j = 0; j < NG; j++) glds16(gsrc[j], &S[0][loff[j]]);
  #pragma unroll
  for (int j = 0; j < NG; j++) glds16(gsrc[j] + 64, &S[1][loff[j]]);
  asm volatile("s_waitcnt vmcnt(%0)" :: "n"(NG) : "memory");
  __builtin_amdgcn_s_barrier();
  asm volatile("" ::: "memory");

  int bufc = 0;
  for (int it = 0; it < NIT; ++it) {
    if (it + 2 < NIT) {
      int bufp = bufc + 2; if (bufp >= 3) bufp -= 3;
      #pragma unroll
      for (int j = 0; j < NG; j++) glds16(gsrc[j] + (it + 2) * 64, &S[bufp][loff[j]]);
    }
    compute(bufc);
    if (it + 1 < NIT) {
      // drain tile it+1's loads; leave tile it+2's (if issued) in flight
      if (it + 2 < NIT) asm volatile("s_waitcnt vmcnt(%0)" :: "n"(NG) : "memory");
      else              asm volatile("s_waitcnt vmcnt(0)" ::: "memory");
      __builtin_amdgcn_s_barrier();
      asm volatile("" ::: "memory");
    }
    bufc = (bufc + 1 == 3) ? 0 : bufc + 1;
  }

  if (EPI == 4) {
    const int reg = n0 / 768;                 // 0=q, 1=k, 2=v (block-uniform)
    if (reg == 2) {
      // LDS-bounce transpose of the v quadrant -> vt (bh, d, l) directly.
      __syncthreads();                        // all waves done reading S
      u16* T = (u16*)&S[0][0];                // [64][130] padded
      #pragma unroll
      for (int mt = 0; mt < MT; mt++)
        #pragma unroll
        for (int nt = 0; nt < NTW; nt++)
          #pragma unroll
          for (int r = 0; r < 4; r++)
            T[(wm + mt * 16 + quad * 4 + r) * 130 + wn + nt * 16 + l16] =
                f2bf(acc[mt][nt][r]);
      __syncthreads();
      int d = t >> 1, lh = (t & 1) * 32;
      int head = ((n0 - 1536) >> 6) + (d >> 6), d63 = d & 63;
      u16 o[32];
      #pragma unroll
      for (int i2 = 0; i2 < 32; i2++) o[i2] = T[(lh + i2) * 130 + d];
      u16* dst = vt + ((size_t)((m0 >> 10) * 12 + head) * 64 + d63) * 1024
                    + (m0 & 1023) + lh;
      #pragma unroll
      for (int i2 = 0; i2 < 4; i2++) *(short8*)(dst + i2 * 8) = *(short8*)&o[i2 * 8];
      return;
    }
    // q/k: fused rmsnorm + rope.  wave quadrant = 32 seq rows x one 64-wide head.
    const int cbase = n0 + wn;
    const int hh  = (cbase - reg * 768) >> 6;
    #pragma unroll
    for (int mt = 0; mt < MT; mt++) {
      #pragma unroll
      for (int r = 0; r < 4; r++) {
        int grow = m0 + wm + mt * 16 + quad * 4 + r;
        int bI = grow >> 10, lI = grow & 1023;
        float s2 = 0.f;
        #pragma unroll
        for (int nt = 0; nt < NTW; nt++) s2 += acc[mt][nt][r] * acc[mt][nt][r];
        #pragma unroll
        for (int o = 1; o < 16; o <<= 1) s2 += __shfl_xor(s2, o);
        float rstd = rsqrtf(s2 * (1.f / 64.f) + 1e-6f);
        const float* sc = reg ? ksc : qsc;
        u16* dst = (reg ? kb : qb) + ((size_t)(bI * 12 + hh) * 1024 + lI) * 64;
        #pragma unroll
        for (int nt = 0; nt < NTW; nt++) {
          int d = nt * 16 + l16;
          float v = acc[mt][nt][r] * rstd * sc[d];
          float cv = petp[((lI * 32) + (d >> 1)) * 2];
          float sv = petp[((lI * 32) + (d >> 1)) * 2 + 1];
          float ov = __shfl_xor(v, 1);
          float rv = (d & 1) ? (sv * ov + cv * v) : (cv * v - sv * ov);
          if (reg == 0) rv *= 0.125f;
          dst[d] = f2bf(rv);
        }
      }
    }
    return;
  }

  #pragma unroll
  for (int mt = 0; mt < MT; mt++) {
    #pragma unroll
    for (int nt = 0; nt < NTW; nt++) {
      int col = n0 + wn + nt * 16 + l16;
      float bcol = bias ? bias[col] : 0.f;
      #pragma unroll
      for (int r = 0; r < 4; r++) {
        int row = m0 + wm + mt * 16 + quad * 4 + r;
        float v = acc[mt][nt][r] + bcol;
        if (EPI == 1) v += extra[(row >> 10) * N + col];
        if (EPI == 2) v += extra[(size_t)row * N + col];
        if (EPI == 3) v = 0.5f * v * (1.f + erff(v * 0.70710678118654752f));
        if (Cf) Cf[(size_t)row * N + col] = v;
        if (Cb) Cb[(size_t)row * N + col] = f2bf(v);
      }
    }
  }
}

// ---------------------------------------------------------------------------
extern "C" void kernel_launch(void* const* d_in, const int* in_sizes, int n_in,
                              void* d_out, int out_size, void* d_ws, size_t ws_size,
                              hipStream_t stream) {
  const float* sf   = (const float*)d_in[0];
  const float* ce   = (const float*)d_in[2];
  const float* sw   = (const float*)d_in[3];
  const float* sb   = (const float*)d_in[4];
  const float* cw   = (const float*)d_in[5];
  const float* cb   = (const float*)d_in[6];
  const float* ln1g = (const float*)d_in[7];
  const float* ln1b = (const float*)d_in[8];
  const float* qkvw = (const float*)d_in[9];
  const float* qsc  = (const float*)d_in[10];
  const float* ksc  = (const float*)d_in[11];
  const float* pw   = (const float*)d_in[12];
  const float* pb   = (const float*)d_in[13];
  const float* ln2g = (const float*)d_in[16];
  const float* ln2b = (const float*)d_in[17];
  const float* w1   = (const float*)d_in[18];
  const float* b1   = (const float*)d_in[19];
  const float* w2   = (const float*)d_in[20];
  const float* b2   = (const float*)d_in[21];
  const float* ow   = (const float*)d_in[22];
  const float* ob   = (const float*)d_in[23];

  char* p = (char*)d_ws;
  auto alloc = [&](size_t bytes) { char* r = p; p += (bytes + 255) & ~(size_t)255; return r; };
  float* pet  = (float*)alloc((size_t)1024 * 32 * 2 * 4);
  u16* swT    = (u16*)alloc((size_t)768 * 768 * 2);
  u16* owT    = (u16*)alloc((size_t)768 * 768 * 2);
  u16* qkvT   = (u16*)alloc((size_t)6 * 2304 * 768 * 2);
  u16* pwT    = (u16*)alloc((size_t)6 * 768 * 768 * 2);
  u16* w1T    = (u16*)alloc((size_t)6 * 3072 * 768 * 2);
  u16* w2T    = (u16*)alloc((size_t)6 * 768 * 3072 * 2);
  u16* sfb    = (u16*)alloc((size_t)2048 * 768 * 2);
  float* cpar = (float*)alloc((size_t)32 * 768 * 4);
  float* cond = (float*)alloc((size_t)2 * 768 * 4);
  float* x    = (float*)alloc((size_t)2048 * 768 * 4);
  u16* xb     = (u16*)alloc((size_t)2048 * 768 * 2);
  u16* h      = (u16*)alloc((size_t)2048 * 768 * 2);
  u16* qbuf   = (u16*)alloc((size_t)2048 * 768 * 2);
  u16* kbuf   = (u16*)alloc((size_t)2048 * 768 * 2);
  u16* vtb    = (u16*)alloc((size_t)2048 * 768 * 2);
  u16* obuf   = (u16*)alloc((size_t)2048 * 768 * 2);
  u16* gbuf   = (u16*)alloc((size_t)2048 * 3072 * 2);

  pe_kernel<<<128, 256, 0, stream>>>(pet);
  twt_kernel<<<dim3(24, 24, 1), 256, 0, stream>>>(sw, swT, 768, 768);
  twt_kernel<<<dim3(24, 24, 1), 256, 0, stream>>>(ow, owT, 768, 768);
  twt_kernel<<<dim3(72, 24, 6), 256, 0, stream>>>(qkvw, qkvT, 768, 2304);
  twt_kernel<<<dim3(24, 24, 6), 256, 0, stream>>>(pw, pwT, 768, 768);
  twt_kernel<<<dim3(96, 24, 6), 256, 0, stream>>>(w1, w1T, 768, 3072);
  twt_kernel<<<dim3(24, 96, 6), 256, 0, stream>>>(w2, w2T, 3072, 768);
  cvt_kernel<<<(2048 * 768) / 256, 256, 0, stream>>>(sf, sfb, 2048 * 768);
  condp_kernel<<<dim3(3, 16), 256, 0, stream>>>(ce, cw, cpar);
  condr_kernel<<<6, 256, 0, stream>>>(cpar, cb, cond);

  gemm_bt<1, 64, 64><<<dim3(12, 32), 256, 0, stream>>>(sfb, swT, sb, cond, x, nullptr,
      2048, 768, 768, nullptr, nullptr, nullptr, nullptr, nullptr, nullptr);

  for (int i = 0; i < 6; i++) {
    ln_kernel<<<2048, 256, 0, stream>>>(x, ln1g + i * 768, ln1b + i * 768, h);
    gemm_bt<4, 64, 128><<<dim3(18, 32), 256, 0, stream>>>(h, qkvT + (size_t)i * 2304 * 768,
        nullptr, nullptr, nullptr, nullptr, 2048, 2304, 768,
        qsc + i * 64, ksc + i * 64, pet, qbuf, kbuf, vtb);
    attn_one<<<dim3(32, 24), 128, 0, stream>>>(qbuf, kbuf, vtb, obuf);
    gemm_bt<2, 64, 64><<<dim3(12, 32), 256, 0, stream>>>(obuf, pwT + (size_t)i * 768 * 768,
        pb + i * 768, x, x, nullptr, 2048, 768, 768,
        nullptr, nullptr, nullptr, nullptr, nullptr, nullptr);
    ln_kernel<<<2048, 256, 0, stream>>>(x, ln2g + i * 768, ln2b + i * 768, h);
    gemm_bt<3, 64, 128><<<dim3(24, 32), 256, 0, stream>>>(h, w1T + (size_t)i * 3072 * 768,
        b1 + i * 3072, nullptr, nullptr, gbuf, 2048, 3072, 768,
        nullptr, nullptr, nullptr, nullptr, nullptr, nullptr);
    gemm_bt<2, 64, 64><<<dim3(12, 32), 256, 0, stream>>>(gbuf, w2T + (size_t)i * 768 * 3072,
        b2 + i * 768, x, x, (i == 5) ? xb : nullptr, 2048, 768, 3072,
        nullptr, nullptr, nullptr, nullptr, nullptr, nullptr);
  }
  gemm_bt<0, 64, 64><<<dim3(12, 32), 256, 0, stream>>>(xb, owT, ob, nullptr, (float*)d_out, nullptr,
      2048, 768, 768, nullptr, nullptr, nullptr, nullptr, nullptr, nullptr);
}